// Round 9
// baseline (133.673 us; speedup 1.0000x reference)
//
#include <hip/hip_runtime.h>
#include <cstdint>
#include <cstddef>

typedef __bf16 bf16;
typedef __bf16 bf16x4 __attribute__((ext_vector_type(4)));
typedef __bf16 bf16x8 __attribute__((ext_vector_type(8)));
typedef float  f32x4  __attribute__((ext_vector_type(4)));
typedef float  f32x16 __attribute__((ext_vector_type(16)));

#define B_  2
#define T_  2048
#define D_  1024
#define H_  16
#define HD_ 64
#define M_  (B_ * T_)   // 4096 rows
#define NQB 16          // T_/128 q-super-blocks

#define GLOAD_LDS(gsrc, ldst) \
    __builtin_amdgcn_global_load_lds( \
        (const __attribute__((address_space(1))) void*)(gsrc), \
        (__attribute__((address_space(3))) void*)(ldst), 16, 0, 0)

// ------- merged prologue: z<4 -> transpose+cast W_z; z==4 -> cast x -------
__global__ void prep_kernel(
    const float* __restrict__ x,  bf16* __restrict__ xb,
    const float* __restrict__ W0, bf16* __restrict__ T0,
    const float* __restrict__ W1, bf16* __restrict__ T1,
    const float* __restrict__ W2, bf16* __restrict__ T2,
    const float* __restrict__ W3, bf16* __restrict__ T3)
{
    if (blockIdx.z == 4) {
        // cast 4.19M floats: 1024 blocks x 256 threads x 4 float4
        const int linear = blockIdx.y * 32 + blockIdx.x;
        const int base = linear * 4096 + threadIdx.x * 4;
        #pragma unroll
        for (int u = 0; u < 4; ++u) {
            const int i = base + u * 1024;
            const float4 v = *reinterpret_cast<const float4*>(x + i);
            bf16x4 o = { (bf16)v.x, (bf16)v.y, (bf16)v.z, (bf16)v.w };
            *reinterpret_cast<bf16x4*>(xb + i) = o;
        }
        return;
    }
    __shared__ float tile[32][33];
    const float* W = blockIdx.z == 0 ? W0 : blockIdx.z == 1 ? W1 : blockIdx.z == 2 ? W2 : W3;
    bf16*       Wt = blockIdx.z == 0 ? T0 : blockIdx.z == 1 ? T1 : blockIdx.z == 2 ? T2 : T3;
    const int tx = threadIdx.x & 31, ty = threadIdx.x >> 5;  // 32 x 8
    const int bx = blockIdx.x * 32, by = blockIdx.y * 32;
    #pragma unroll
    for (int r = 0; r < 32; r += 8)
        tile[ty + r][tx] = W[(size_t)(by + ty + r) * D_ + bx + tx];
    __syncthreads();
    #pragma unroll
    for (int r = 0; r < 32; r += 8)
        Wt[(size_t)(bx + ty + r) * D_ + by + tx] = (bf16)tile[tx][ty + r];
}

// ======== 128x128 bf16 GEMM core: 32x32x16 MFMA, 2-phase dbuf, T2 swizzle ========
__device__ __forceinline__ void gemm_128_2ph(
    const bf16* __restrict__ A, const bf16* __restrict__ Bt,
    int m0, int n0, bf16 (*As)[128][64], bf16 (*Bs)[128][64], f32x16 acc[2][2])
{
    constexpr int K = D_;
    constexpr int NK = K / 64;
    const int tid  = threadIdx.x;
    const int wave = tid >> 6, lane = tid & 63;
    const int l5 = lane & 31, hi = lane >> 5;
    const int wr = wave >> 1, wc = wave & 1;

    const int rseg = lane >> 3;              // 0..7
    const int srcc = (lane & 7) ^ rseg;      // pre-swizzled source chunk

    auto stage = [&](int b, int k0) {
        #pragma unroll
        for (int cc = 0; cc < 4; ++cc) {
            const int c   = wave * 4 + cc;
            const int row = c * 8 + rseg;
            GLOAD_LDS(A  + (size_t)(m0 + row) * K + k0 + srcc * 8, &As[b][c * 8][0]);
            GLOAD_LDS(Bt + (size_t)(n0 + row) * K + k0 + srcc * 8, &Bs[b][c * 8][0]);
        }
    };

    stage(0, 0);
    __syncthreads();

    #pragma unroll 1
    for (int t = 0; t < NK; ++t) {
        const int cur = t & 1;
        if (t + 1 < NK) stage(cur ^ 1, (t + 1) * 64);   // prefetch next tile first

        bf16x8 af[2][4], bfr[2][4];
        #pragma unroll
        for (int mi = 0; mi < 2; ++mi)
            #pragma unroll
            for (int ks = 0; ks < 4; ++ks) {
                const int row = wr * 64 + mi * 32 + l5;
                af[mi][ks] = *reinterpret_cast<const bf16x8*>(
                    &As[cur][row][((ks * 2 + hi) ^ (row & 7)) * 8]);
            }
        #pragma unroll
        for (int nj = 0; nj < 2; ++nj)
            #pragma unroll
            for (int ks = 0; ks < 4; ++ks) {
                const int row = wc * 64 + nj * 32 + l5;
                bfr[nj][ks] = *reinterpret_cast<const bf16x8*>(
                    &Bs[cur][row][((ks * 2 + hi) ^ (row & 7)) * 8]);
            }
        __builtin_amdgcn_s_setprio(1);
        #pragma unroll
        for (int mi = 0; mi < 2; ++mi)
            #pragma unroll
            for (int nj = 0; nj < 2; ++nj)
                #pragma unroll
                for (int ks = 0; ks < 4; ++ks)
                    acc[mi][nj] = __builtin_amdgcn_mfma_f32_32x32x16_bf16(
                        af[mi][ks], bfr[nj][ks], acc[mi][nj], 0, 0, 0);
        __builtin_amdgcn_s_setprio(0);
        __syncthreads();
    }
}

// ================= fused QKV projection, 128^2 tiles, 768 blocks =================
__global__ __launch_bounds__(256, 2) void qkv128_kernel(
    const bf16* __restrict__ xb,
    const bf16* __restrict__ WqT, const float* __restrict__ bq, bf16* __restrict__ Qo,
    const bf16* __restrict__ WkT, const float* __restrict__ bk, bf16* __restrict__ Ko,
    const bf16* __restrict__ WvT, const float* __restrict__ bv, bf16* __restrict__ Vt)
{
    __shared__ bf16 As[2][128][64];   // 32 KB
    __shared__ bf16 Bs[2][128][64];   // 32 KB

    const int bid = blockIdx.x;
    const int swz = (bid & 7) * 96 + (bid >> 3);   // XCD-bijective (768 % 8 == 0)

    const bf16 *Aop, *Bop;
    const float *bias;
    bf16 *outp;
    float scale = 1.0f;
    int m0, n0, mode;
    if (swz < 512) {
        const int bm = swz & 31, bn = swz >> 5;    // bm 0..31 (tokens), bn 0..15 (Q|K)
        m0 = bm * 128;
        Aop = xb;
        if (bn < 8) { Bop = WqT; n0 = bn * 128;       bias = bq; outp = Qo; scale = 0.125f; }
        else        { Bop = WkT; n0 = (bn - 8) * 128; bias = bk; outp = Ko; }
        mode = 0;
    } else {
        const int v = swz - 512, bm = v & 7, bn = v >> 3;  // bm 0..7 (d), bn 0..31 (tokens)
        m0 = bm * 128; n0 = bn * 128;
        Aop = WvT; Bop = xb; bias = bv; outp = Vt; mode = 1;
    }

    f32x16 acc[2][2] = {};
    gemm_128_2ph(Aop, Bop, m0, n0, As, Bs, acc);

    const int lane = threadIdx.x & 63, wave = threadIdx.x >> 6;
    const int l5 = lane & 31, hi = lane >> 5;
    const int wr = wave >> 1, wc = wave & 1;
    if (mode == 0) {
        #pragma unroll
        for (int mi = 0; mi < 2; ++mi)
            #pragma unroll
            for (int nj = 0; nj < 2; ++nj)
                #pragma unroll
                for (int q = 0; q < 16; ++q) {
                    const int m = m0 + wr * 64 + mi * 32 + (q & 3) + 8 * (q >> 2) + 4 * hi;
                    const int n = n0 + wc * 64 + nj * 32 + l5;
                    const float val = (acc[mi][nj][q] + bias[n]) * scale;
                    const int b = m >> 11, t = m & (T_ - 1);
                    const int h = n >> 6, hd = n & 63;
                    outp[((size_t)((b * H_ + h) * T_ + t)) * HD_ + hd] = (bf16)val;
                }
    } else {
        #pragma unroll
        for (int mi = 0; mi < 2; ++mi)
            #pragma unroll
            for (int nj = 0; nj < 2; ++nj)
                #pragma unroll
                for (int q = 0; q < 16; ++q) {
                    const int d = m0 + wr * 64 + mi * 32 + (q & 3) + 8 * (q >> 2) + 4 * hi;
                    const int n = n0 + wc * 64 + nj * 32 + l5;
                    const float val = acc[mi][nj][q] + bias[d];
                    const int b = n >> 11, t = n & (T_ - 1);
                    outp[((size_t)(b * D_ + d)) * T_ + t] = (bf16)val;
                }
    }
}

// ---------------- out projection: fp32 [m][n] ----------------
__global__ __launch_bounds__(256, 2) void gemm_out_kernel(
    const bf16* __restrict__ A, const bf16* __restrict__ WoT,
    const float* __restrict__ bo, float* __restrict__ Out)
{
    __shared__ bf16 As[2][128][64];
    __shared__ bf16 Bs[2][128][64];
    const int m0 = blockIdx.x * 128, n0 = blockIdx.y * 128;

    f32x16 acc[2][2] = {};
    gemm_128_2ph(A, WoT, m0, n0, As, Bs, acc);

    const int lane = threadIdx.x & 63, wave = threadIdx.x >> 6;
    const int l5 = lane & 31, hi = lane >> 5;
    const int wr = wave >> 1, wc = wave & 1;
    #pragma unroll
    for (int mi = 0; mi < 2; ++mi)
        #pragma unroll
        for (int nj = 0; nj < 2; ++nj)
            #pragma unroll
            for (int q = 0; q < 16; ++q) {
                const int m = m0 + wr * 64 + mi * 32 + (q & 3) + 8 * (q >> 2) + 4 * hi;
                const int n = n0 + wc * 64 + nj * 32 + l5;
                Out[(size_t)m * D_ + n] = acc[mi][nj][q] + bo[n];
            }
}

// ======= flash attention: both paired halves (qb, 15-qb) share one tile loop =======
// Grid (8, 32). Each staged K/V tile feeds TWO independent QK->softmax->PV chains
// (T15 mechanism: one half's MFMA overlaps the other's VALU between barriers).
__global__ __launch_bounds__(512) void attn_kernel(
    const bf16* __restrict__ Q, const bf16* __restrict__ K,
    const bf16* __restrict__ Vt, bf16* __restrict__ Out)
{
    const int bh = blockIdx.y;
    const int tid = threadIdx.x, wave = tid >> 6, lane = tid & 63;
    const int lr = lane & 15, lg = lane >> 4;
    const size_t kbase = (size_t)bh * T_ * HD_;   // Q,K
    const size_t vbase = (size_t)bh * HD_ * T_;   // Vt

    __shared__ bf16 Ks[2][64][64];      // 16 KB
    __shared__ bf16 Vs[2][64][64];      // 16 KB  (Vs[buf][d][key])
    __shared__ bf16 Ps[2][8][16][72];   // 36 KB  per-half per-wave P[q][key]

    auto stage = [&](int sb, int kt) {
        const int kv0 = kt * 64;
        const int rseg = lane >> 3;
        const int srcw = (lane & 7) ^ rseg;      // XOR source-chunk swizzle (involution)
        const int row  = wave * 8 + rseg;
        GLOAD_LDS(K  + kbase + (size_t)(kv0 + row) * HD_ + srcw * 8, &Ks[sb][wave * 8][0]);
        GLOAD_LDS(Vt + vbase + (size_t)row * T_ + kv0 + srcw * 8,    &Vs[sb][wave * 8][0]);
    };
    auto kfrag = [&](int sb, int row, int chunk) {
        return *reinterpret_cast<const bf16x8*>(&Ks[sb][row][(chunk ^ (row & 7)) * 8]);
    };
    auto vfrag = [&](int sb, int row, int chunk) {
        return *reinterpret_cast<const bf16x8*>(&Vs[sb][row][(chunk ^ (row & 7)) * 8]);
    };

    const int qbL = blockIdx.x;            // 0..7  (light half)
    const int qbH = NQB - 1 - blockIdx.x;  // 8..15 (heavy half)
    const int q0L = qbL * 128, q0H = qbH * 128;
    const int nt  = 2 * qbH + 2;
    const int qw  = wave * 16;

    // Q fragments for both halves (B-operand: col=lane&15 -> q=lr)
    bf16x8 qfL[2], qfH[2];
    {
        const bf16* qrow = Q + kbase + (size_t)(q0L + qw + lr) * HD_;
        qfL[0] = *reinterpret_cast<const bf16x8*>(qrow + lg * 8);
        qfL[1] = *reinterpret_cast<const bf16x8*>(qrow + 32 + lg * 8);
        const bf16* qrow2 = Q + kbase + (size_t)(q0H + qw + lr) * HD_;
        qfH[0] = *reinterpret_cast<const bf16x8*>(qrow2 + lg * 8);
        qfH[1] = *reinterpret_cast<const bf16x8*>(qrow2 + 32 + lg * 8);
    }

    float mL = -1e30f, lL = 0.f, mH = -1e30f, lH = 0.f;
    f32x4 oL[4] = {}, oH[4] = {};

    stage(0, 0);
    __syncthreads();

    #pragma unroll 1
    for (int t = 0; t < nt; ++t) {
        const int cur = t & 1;
        if (t + 1 < nt) stage(cur ^ 1, t + 1);   // prefetch next tile

        const int kv0 = t * 64;
        const bool actL = kv0 <= q0L + qw + 15;  // wave-uniform
        const bool actH = kv0 <= q0H + qw + 15;

        f32x4 sL[4], sH[4];
        // ---- QK^T for both halves (independent MFMA chains) ----
        __builtin_amdgcn_s_setprio(1);
        if (actH) {
            #pragma unroll
            for (int n16 = 0; n16 < 4; ++n16) {
                sH[n16] = f32x4{};
                #pragma unroll
                for (int kk = 0; kk < 2; ++kk)
                    sH[n16] = __builtin_amdgcn_mfma_f32_16x16x32_bf16(
                        kfrag(cur, n16 * 16 + lr, kk * 4 + lg), qfH[kk], sH[n16], 0, 0, 0);
            }
        }
        if (actL) {
            #pragma unroll
            for (int n16 = 0; n16 < 4; ++n16) {
                sL[n16] = f32x4{};
                #pragma unroll
                for (int kk = 0; kk < 2; ++kk)
                    sL[n16] = __builtin_amdgcn_mfma_f32_16x16x32_bf16(
                        kfrag(cur, n16 * 16 + lr, kk * 4 + lg), qfL[kk], sL[n16], 0, 0, 0);
            }
        }
        __builtin_amdgcn_s_setprio(0);

        // ---- softmax + P-write, half H ----
        if (actH) {
            if (t >= 2 * qbH) {
                #pragma unroll
                for (int n16 = 0; n16 < 4; ++n16)
                    #pragma unroll
                    for (int r = 0; r < 4; ++r)
                        if (kv0 + n16 * 16 + lg * 4 + r > q0H + qw + lr) sH[n16][r] = -1e30f;
            }
            float mx = sH[0][0];
            #pragma unroll
            for (int n16 = 0; n16 < 4; ++n16)
                #pragma unroll
                for (int r = 0; r < 4; ++r) mx = fmaxf(mx, sH[n16][r]);
            mx = fmaxf(mx, __shfl_xor(mx, 16));
            mx = fmaxf(mx, __shfl_xor(mx, 32));
            if (__any(mx > mH + 8.0f)) {
                const float mnew = fmaxf(mH, mx);
                const float alpha = __expf(mH - mnew);
                #pragma unroll
                for (int r = 0; r < 4; ++r) {
                    const float a = __shfl(alpha, lg * 4 + r);
                    #pragma unroll
                    for (int nd = 0; nd < 4; ++nd) oH[nd][r] *= a;
                }
                lH *= alpha; mH = mnew;
            }
            float rs = 0.f;
            #pragma unroll
            for (int n16 = 0; n16 < 4; ++n16) {
                bf16x4 pw;
                #pragma unroll
                for (int r = 0; r < 4; ++r) {
                    const float p = __expf(sH[n16][r] - mH);
                    rs += p; pw[r] = (bf16)p;
                }
                *reinterpret_cast<bf16x4*>(&Ps[1][wave][lr][n16 * 16 + lg * 4]) = pw;
            }
            rs += __shfl_xor(rs, 16);
            rs += __shfl_xor(rs, 32);
            lH += rs;
        }
        // ---- softmax + P-write, half L ----
        if (actL) {
            if (t >= 2 * qbL) {
                #pragma unroll
                for (int n16 = 0; n16 < 4; ++n16)
                    #pragma unroll
                    for (int r = 0; r < 4; ++r)
                        if (kv0 + n16 * 16 + lg * 4 + r > q0L + qw + lr) sL[n16][r] = -1e30f;
            }
            float mx = sL[0][0];
            #pragma unroll
            for (int n16 = 0; n16 < 4; ++n16)
                #pragma unroll
                for (int r = 0; r < 4; ++r) mx = fmaxf(mx, sL[n16][r]);
            mx = fmaxf(mx, __shfl_xor(mx, 16));
            mx = fmaxf(mx, __shfl_xor(mx, 32));
            if (__any(mx > mL + 8.0f)) {
                const float mnew = fmaxf(mL, mx);
                const float alpha = __expf(mL - mnew);
                #pragma unroll
                for (int r = 0; r < 4; ++r) {
                    const float a = __shfl(alpha, lg * 4 + r);
                    #pragma unroll
                    for (int nd = 0; nd < 4; ++nd) oL[nd][r] *= a;
                }
                lL *= alpha; mL = mnew;
            }
            float rs = 0.f;
            #pragma unroll
            for (int n16 = 0; n16 < 4; ++n16) {
                bf16x4 pw;
                #pragma unroll
                for (int r = 0; r < 4; ++r) {
                    const float p = __expf(sL[n16][r] - mL);
                    rs += p; pw[r] = (bf16)p;
                }
                *reinterpret_cast<bf16x4*>(&Ps[0][wave][lr][n16 * 16 + lg * 4]) = pw;
            }
            rs += __shfl_xor(rs, 16);
            rs += __shfl_xor(rs, 32);
            lL += rs;
        }

        // ---- PV for both halves ----
        __builtin_amdgcn_s_setprio(1);
        if (actH) {
            #pragma unroll
            for (int ks = 0; ks < 2; ++ks) {
                const bf16x8 pa = *reinterpret_cast<const bf16x8*>(&Ps[1][wave][lr][ks * 32 + lg * 8]);
                #pragma unroll
                for (int nd = 0; nd < 4; ++nd)
                    oH[nd] = __builtin_amdgcn_mfma_f32_16x16x32_bf16(
                        pa, vfrag(cur, nd * 16 + lr, ks * 4 + lg), oH[nd], 0, 0, 0);
            }
        }
        if (actL) {
            #pragma unroll
            for (int ks = 0; ks < 2; ++ks) {
                const bf16x8 pa = *reinterpret_cast<const bf16x8*>(&Ps[0][wave][lr][ks * 32 + lg * 8]);
                #pragma unroll
                for (int nd = 0; nd < 4; ++nd)
                    oL[nd] = __builtin_amdgcn_mfma_f32_16x16x32_bf16(
                        pa, vfrag(cur, nd * 16 + lr, ks * 4 + lg), oL[nd], 0, 0, 0);
            }
        }
        __builtin_amdgcn_s_setprio(0);
        __syncthreads();   // all reads of cur done; next tile fully staged
    }

    // ---- normalize + store both halves to [b*T+t][h*64+d] ----
    const int b = bh >> 4, h = bh & 15;
    {
        const float linv = 1.0f / lL;
        #pragma unroll
        for (int r = 0; r < 4; ++r) {
            const float li = __shfl(linv, lg * 4 + r);
            const int q = q0L + qw + lg * 4 + r;
            #pragma unroll
            for (int nd = 0; nd < 4; ++nd)
                Out[((size_t)(b * T_ + q)) * D_ + h * HD_ + nd * 16 + lr] = (bf16)(oL[nd][r] * li);
        }
    }
    {
        const float linv = 1.0f / lH;
        #pragma unroll
        for (int r = 0; r < 4; ++r) {
            const float li = __shfl(linv, lg * 4 + r);
            const int q = q0H + qw + lg * 4 + r;
            #pragma unroll
            for (int nd = 0; nd < 4; ++nd)
                Out[((size_t)(b * T_ + q)) * D_ + h * HD_ + nd * 16 + lr] = (bf16)(oH[nd][r] * li);
        }
    }
}

// ---------------- launch ----------------
extern "C" void kernel_launch(void* const* d_in, const int* in_sizes, int n_in,
                              void* d_out, int out_size, void* d_ws, size_t ws_size,
                              hipStream_t stream) {
    const float* x  = (const float*)d_in[0];
    const float* Wq = (const float*)d_in[1];
    const float* bq = (const float*)d_in[2];
    const float* Wk = (const float*)d_in[3];
    const float* bk = (const float*)d_in[4];
    const float* Wv = (const float*)d_in[5];
    const float* bv = (const float*)d_in[6];
    const float* Wo = (const float*)d_in[7];
    const float* bo = (const float*)d_in[8];
    float* out = (float*)d_out;

    char* ws = (char*)d_ws;
    bf16* xb   = (bf16*)(ws);                         // 8 MB  [4096][1024]
    bf16* WqT  = (bf16*)(ws + ( 8u << 20));           // 2 MB  [1024][1024]
    bf16* WkT  = (bf16*)(ws + (10u << 20));
    bf16* WvT  = (bf16*)(ws + (12u << 20));
    bf16* WoT  = (bf16*)(ws + (14u << 20));
    bf16* Qb   = (bf16*)(ws + (16u << 20));           // 8 MB  [32][2048][64]
    bf16* Kb   = (bf16*)(ws + (24u << 20));
    bf16* Vtb  = (bf16*)(ws + (32u << 20));           // 8 MB  [32][64][2048]
    bf16* attn = (bf16*)(ws + (40u << 20));           // 8 MB  [4096][1024]

    prep_kernel<<<dim3(32, 32, 5), 256, 0, stream>>>(
        x, xb, Wq, WqT, Wk, WkT, Wv, WvT, Wo, WoT);

    qkv128_kernel<<<768, 256, 0, stream>>>(xb, WqT, bq, Qb, WkT, bk, Kb, WvT, bv, Vtb);

    attn_kernel<<<dim3(NQB / 2, 32), 512, 0, stream>>>(Qb, Kb, Vtb, attn);

    gemm_out_kernel<<<dim3(32, 8), 256, 0, stream>>>(attn, WoT, bo, out);
}

// Round 10
// 126.888 us; speedup vs baseline: 1.0535x; 1.0535x over previous
//
#include <hip/hip_runtime.h>
#include <cstdint>
#include <cstddef>

typedef __bf16 bf16;
typedef __bf16 bf16x4 __attribute__((ext_vector_type(4)));
typedef __bf16 bf16x8 __attribute__((ext_vector_type(8)));
typedef float  f32x4  __attribute__((ext_vector_type(4)));
typedef float  f32x16 __attribute__((ext_vector_type(16)));

#define B_  2
#define T_  2048
#define D_  1024
#define H_  16
#define HD_ 64
#define M_  (B_ * T_)   // 4096 rows
#define NQB 32          // T_/64 q-blocks

#define GLOAD_LDS(gsrc, ldst) \
    __builtin_amdgcn_global_load_lds( \
        (const __attribute__((address_space(1))) void*)(gsrc), \
        (__attribute__((address_space(3))) void*)(ldst), 16, 0, 0)

// ------- merged prologue: z<4 -> transpose+cast W_z; z==4 -> cast x -------
__global__ void prep_kernel(
    const float* __restrict__ x,  bf16* __restrict__ xb,
    const float* __restrict__ W0, bf16* __restrict__ T0,
    const float* __restrict__ W1, bf16* __restrict__ T1,
    const float* __restrict__ W2, bf16* __restrict__ T2,
    const float* __restrict__ W3, bf16* __restrict__ T3)
{
    if (blockIdx.z == 4) {
        const int linear = blockIdx.y * 32 + blockIdx.x;
        const int base = linear * 4096 + threadIdx.x * 4;
        #pragma unroll
        for (int u = 0; u < 4; ++u) {
            const int i = base + u * 1024;
            const float4 v = *reinterpret_cast<const float4*>(x + i);
            bf16x4 o = { (bf16)v.x, (bf16)v.y, (bf16)v.z, (bf16)v.w };
            *reinterpret_cast<bf16x4*>(xb + i) = o;
        }
        return;
    }
    __shared__ float tile[32][33];
    const float* W = blockIdx.z == 0 ? W0 : blockIdx.z == 1 ? W1 : blockIdx.z == 2 ? W2 : W3;
    bf16*       Wt = blockIdx.z == 0 ? T0 : blockIdx.z == 1 ? T1 : blockIdx.z == 2 ? T2 : T3;
    const int tx = threadIdx.x & 31, ty = threadIdx.x >> 5;  // 32 x 8
    const int bx = blockIdx.x * 32, by = blockIdx.y * 32;
    #pragma unroll
    for (int r = 0; r < 32; r += 8)
        tile[ty + r][tx] = W[(size_t)(by + ty + r) * D_ + bx + tx];
    __syncthreads();
    #pragma unroll
    for (int r = 0; r < 32; r += 8)
        Wt[(size_t)(bx + ty + r) * D_ + by + tx] = (bf16)tile[tx][ty + r];
}

// ======== 128x128 bf16 GEMM core: 32x32x16 MFMA, 2-phase dbuf, T2 swizzle ========
__device__ __forceinline__ void gemm_128_2ph(
    const bf16* __restrict__ A, const bf16* __restrict__ Bt,
    int m0, int n0, bf16 (*As)[128][64], bf16 (*Bs)[128][64], f32x16 acc[2][2])
{
    constexpr int K = D_;
    constexpr int NK = K / 64;
    const int tid  = threadIdx.x;
    const int wave = tid >> 6, lane = tid & 63;
    const int l5 = lane & 31, hi = lane >> 5;
    const int wr = wave >> 1, wc = wave & 1;

    const int rseg = lane >> 3;              // 0..7
    const int srcc = (lane & 7) ^ rseg;      // pre-swizzled source chunk

    auto stage = [&](int b, int k0) {
        #pragma unroll
        for (int cc = 0; cc < 4; ++cc) {
            const int c   = wave * 4 + cc;
            const int row = c * 8 + rseg;
            GLOAD_LDS(A  + (size_t)(m0 + row) * K + k0 + srcc * 8, &As[b][c * 8][0]);
            GLOAD_LDS(Bt + (size_t)(n0 + row) * K + k0 + srcc * 8, &Bs[b][c * 8][0]);
        }
    };

    stage(0, 0);
    __syncthreads();

    #pragma unroll 1
    for (int t = 0; t < NK; ++t) {
        const int cur = t & 1;
        if (t + 1 < NK) stage(cur ^ 1, (t + 1) * 64);   // prefetch next tile first

        bf16x8 af[2][4], bfr[2][4];
        #pragma unroll
        for (int mi = 0; mi < 2; ++mi)
            #pragma unroll
            for (int ks = 0; ks < 4; ++ks) {
                const int row = wr * 64 + mi * 32 + l5;
                af[mi][ks] = *reinterpret_cast<const bf16x8*>(
                    &As[cur][row][((ks * 2 + hi) ^ (row & 7)) * 8]);
            }
        #pragma unroll
        for (int nj = 0; nj < 2; ++nj)
            #pragma unroll
            for (int ks = 0; ks < 4; ++ks) {
                const int row = wc * 64 + nj * 32 + l5;
                bfr[nj][ks] = *reinterpret_cast<const bf16x8*>(
                    &Bs[cur][row][((ks * 2 + hi) ^ (row & 7)) * 8]);
            }
        __builtin_amdgcn_s_setprio(1);
        #pragma unroll
        for (int mi = 0; mi < 2; ++mi)
            #pragma unroll
            for (int nj = 0; nj < 2; ++nj)
                #pragma unroll
                for (int ks = 0; ks < 4; ++ks)
                    acc[mi][nj] = __builtin_amdgcn_mfma_f32_32x32x16_bf16(
                        af[mi][ks], bfr[nj][ks], acc[mi][nj], 0, 0, 0);
        __builtin_amdgcn_s_setprio(0);
        __syncthreads();
    }
}

// ================= fused QKV projection, 128^2 tiles, 768 blocks =================
__global__ __launch_bounds__(256, 2) void qkv128_kernel(
    const bf16* __restrict__ xb,
    const bf16* __restrict__ WqT, const float* __restrict__ bq, bf16* __restrict__ Qo,
    const bf16* __restrict__ WkT, const float* __restrict__ bk, bf16* __restrict__ Ko,
    const bf16* __restrict__ WvT, const float* __restrict__ bv, bf16* __restrict__ Vt)
{
    __shared__ bf16 As[2][128][64];   // 32 KB
    __shared__ bf16 Bs[2][128][64];   // 32 KB

    const int bid = blockIdx.x;
    const int swz = (bid & 7) * 96 + (bid >> 3);   // XCD-bijective (768 % 8 == 0)

    const bf16 *Aop, *Bop;
    const float *bias;
    bf16 *outp;
    float scale = 1.0f;
    int m0, n0, mode;
    if (swz < 512) {
        const int bm = swz & 31, bn = swz >> 5;    // bm 0..31 (tokens), bn 0..15 (Q|K)
        m0 = bm * 128;
        Aop = xb;
        if (bn < 8) { Bop = WqT; n0 = bn * 128;       bias = bq; outp = Qo; scale = 0.125f; }
        else        { Bop = WkT; n0 = (bn - 8) * 128; bias = bk; outp = Ko; }
        mode = 0;
    } else {
        const int v = swz - 512, bm = v & 7, bn = v >> 3;  // bm 0..7 (d), bn 0..31 (tokens)
        m0 = bm * 128; n0 = bn * 128;
        Aop = WvT; Bop = xb; bias = bv; outp = Vt; mode = 1;
    }

    f32x16 acc[2][2] = {};
    gemm_128_2ph(Aop, Bop, m0, n0, As, Bs, acc);

    const int lane = threadIdx.x & 63, wave = threadIdx.x >> 6;
    const int l5 = lane & 31, hi = lane >> 5;
    const int wr = wave >> 1, wc = wave & 1;
    if (mode == 0) {
        #pragma unroll
        for (int mi = 0; mi < 2; ++mi)
            #pragma unroll
            for (int nj = 0; nj < 2; ++nj)
                #pragma unroll
                for (int q = 0; q < 16; ++q) {
                    const int m = m0 + wr * 64 + mi * 32 + (q & 3) + 8 * (q >> 2) + 4 * hi;
                    const int n = n0 + wc * 64 + nj * 32 + l5;
                    const float val = (acc[mi][nj][q] + bias[n]) * scale;
                    const int b = m >> 11, t = m & (T_ - 1);
                    const int h = n >> 6, hd = n & 63;
                    outp[((size_t)((b * H_ + h) * T_ + t)) * HD_ + hd] = (bf16)val;
                }
    } else {
        #pragma unroll
        for (int mi = 0; mi < 2; ++mi)
            #pragma unroll
            for (int nj = 0; nj < 2; ++nj)
                #pragma unroll
                for (int q = 0; q < 16; ++q) {
                    const int d = m0 + wr * 64 + mi * 32 + (q & 3) + 8 * (q >> 2) + 4 * hi;
                    const int n = n0 + wc * 64 + nj * 32 + l5;
                    const float val = acc[mi][nj][q] + bias[d];
                    const int b = n >> 11, t = n & (T_ - 1);
                    outp[((size_t)(b * D_ + d)) * T_ + t] = (bf16)val;
                }
    }
}

// ---------------- out projection: fp32 [m][n] ----------------
__global__ __launch_bounds__(256, 2) void gemm_out_kernel(
    const bf16* __restrict__ A, const bf16* __restrict__ WoT,
    const float* __restrict__ bo, float* __restrict__ Out)
{
    __shared__ bf16 As[2][128][64];
    __shared__ bf16 Bs[2][128][64];
    const int m0 = blockIdx.x * 128, n0 = blockIdx.y * 128;

    f32x16 acc[2][2] = {};
    gemm_128_2ph(A, WoT, m0, n0, As, Bs, acc);

    const int lane = threadIdx.x & 63, wave = threadIdx.x >> 6;
    const int l5 = lane & 31, hi = lane >> 5;
    const int wr = wave >> 1, wc = wave & 1;
    #pragma unroll
    for (int mi = 0; mi < 2; ++mi)
        #pragma unroll
        for (int nj = 0; nj < 2; ++nj)
            #pragma unroll
            for (int q = 0; q < 16; ++q) {
                const int m = m0 + wr * 64 + mi * 32 + (q & 3) + 8 * (q >> 2) + 4 * hi;
                const int n = n0 + wc * 64 + nj * 32 + l5;
                Out[(size_t)m * D_ + n] = acc[mi][nj][q] + bo[n];
            }
}

// ======= flash attention: QBLK=64, 4 waves, 512 blocks (2/CU), XCD-grouped =======
// Block handles q-blocks p and 31-p sequentially (34 staged tiles, uniform).
// Decode: xcd = bid&7, bh = xcd*4 + (bid>>3)/16, pair = (bid>>3)%16 -> all 16
// pair-blocks of a bh (and a 2nd bh) on ONE XCD -> K/V served from its L2.
__global__ __launch_bounds__(256) void attn_kernel(
    const bf16* __restrict__ Q, const bf16* __restrict__ K,
    const bf16* __restrict__ Vt, bf16* __restrict__ Out)
{
    const int bid = blockIdx.x;
    const int xcd = bid & 7, j = bid >> 3;       // j 0..63
    const int bh  = xcd * 4 + (j >> 4);          // 4 bh per XCD
    const int pr  = j & 15;                      // pair index 0..15

    const int tid = threadIdx.x, wave = tid >> 6, lane = tid & 63;  // 4 waves
    const int lr = lane & 15, lg = lane >> 4;
    const size_t kbase = (size_t)bh * T_ * HD_;   // Q,K
    const size_t vbase = (size_t)bh * HD_ * T_;   // Vt

    __shared__ bf16 Ks[2][64][64];   // 16 KB
    __shared__ bf16 Vs[2][64][64];   // 16 KB  (Vs[buf][d][key])
    __shared__ bf16 Ps[4][16][72];   // 9 KB   per-wave P[q][key], padded

    auto stage = [&](int sb, int kt) {
        const int kv0 = kt * 64;
        const int rseg = lane >> 3;
        const int srcw = (lane & 7) ^ rseg;      // XOR source-chunk swizzle (involution)
        #pragma unroll
        for (int cc = 0; cc < 2; ++cc) {
            const int seg = wave * 2 + cc;       // 0..7
            const int row = seg * 8 + rseg;      // 0..63
            GLOAD_LDS(K  + kbase + (size_t)(kv0 + row) * HD_ + srcw * 8, &Ks[sb][seg * 8][0]);
            GLOAD_LDS(Vt + vbase + (size_t)row * T_ + kv0 + srcw * 8,    &Vs[sb][seg * 8][0]);
        }
    };
    auto kfrag = [&](int sb, int row, int chunk) {
        return *reinterpret_cast<const bf16x8*>(&Ks[sb][row][(chunk ^ (row & 7)) * 8]);
    };
    auto vfrag = [&](int sb, int row, int chunk) {
        return *reinterpret_cast<const bf16x8*>(&Vs[sb][row][(chunk ^ (row & 7)) * 8]);
    };

    #pragma unroll 1
    for (int half = 0; half < 2; ++half) {
        const int qb = half == 0 ? pr : (NQB - 1 - pr);
        const int q0 = qb * 64;
        const int nt = qb + 1;                   // tiles 0..qb (t<=qb always active)
        const int qw = wave * 16;

        // Q fragments for this wave's 16 rows (B-operand: col=lane&15 -> q=lr)
        bf16x8 qf[2];
        {
            const bf16* qrow = Q + kbase + (size_t)(q0 + qw + lr) * HD_;
            qf[0] = *reinterpret_cast<const bf16x8*>(qrow + lg * 8);
            qf[1] = *reinterpret_cast<const bf16x8*>(qrow + 32 + lg * 8);
        }

        float m_s = -1e30f, l_s = 0.f;           // softmax state for q = q0+qw+lr
        f32x4 o_acc[4] = {};                     // O[q=qw+lg*4+r][d=nd*16+lr]

        stage(0, 0);
        __syncthreads();

        #pragma unroll 1
        for (int t = 0; t < nt; ++t) {
            const int cur = t & 1;
            if (t + 1 < nt) stage(cur ^ 1, t + 1);   // prefetch next tile

            const int kv0 = t * 64;
            // S'[key][q]: key = kv0 + n16*16 + lg*4 + r, q = q0 + qw + lr
            f32x4 s[4] = {};
            __builtin_amdgcn_s_setprio(1);
            #pragma unroll
            for (int n16 = 0; n16 < 4; ++n16)
                #pragma unroll
                for (int kk = 0; kk < 2; ++kk)
                    s[n16] = __builtin_amdgcn_mfma_f32_16x16x32_bf16(
                        kfrag(cur, n16 * 16 + lr, kk * 4 + lg), qf[kk], s[n16], 0, 0, 0);
            __builtin_amdgcn_s_setprio(0);
            if (t == qb) {                       // causal mask on diagonal tile
                #pragma unroll
                for (int n16 = 0; n16 < 4; ++n16)
                    #pragma unroll
                    for (int r = 0; r < 4; ++r)
                        if (kv0 + n16 * 16 + lg * 4 + r > q0 + qw + lr)
                            s[n16][r] = -1e30f;
            }
            // online softmax with defer-max (T13, THR=8)
            float mx = s[0][0];
            #pragma unroll
            for (int n16 = 0; n16 < 4; ++n16)
                #pragma unroll
                for (int r = 0; r < 4; ++r)
                    mx = fmaxf(mx, s[n16][r]);
            mx = fmaxf(mx, __shfl_xor(mx, 16));
            mx = fmaxf(mx, __shfl_xor(mx, 32));
            if (__any(mx > m_s + 8.0f)) {
                const float mnew  = fmaxf(m_s, mx);
                const float alpha = __expf(m_s - mnew);
                #pragma unroll
                for (int r = 0; r < 4; ++r) {
                    const float a = __shfl(alpha, lg * 4 + r);
                    #pragma unroll
                    for (int nd = 0; nd < 4; ++nd) o_acc[nd][r] *= a;
                }
                l_s *= alpha;
                m_s = mnew;
            }
            float rs = 0.f;
            #pragma unroll
            for (int n16 = 0; n16 < 4; ++n16) {
                bf16x4 pw;
                #pragma unroll
                for (int r = 0; r < 4; ++r) {
                    const float p = __expf(s[n16][r] - m_s);   // bounded by e^8
                    rs += p;
                    pw[r] = (bf16)p;
                }
                *reinterpret_cast<bf16x4*>(&Ps[wave][lr][n16 * 16 + lg * 4]) = pw;
            }
            rs += __shfl_xor(rs, 16);
            rs += __shfl_xor(rs, 32);
            l_s += rs;
            // O += P @ V
            __builtin_amdgcn_s_setprio(1);
            #pragma unroll
            for (int ks = 0; ks < 2; ++ks) {
                const bf16x8 pa = *reinterpret_cast<const bf16x8*>(&Ps[wave][lr][ks * 32 + lg * 8]);
                #pragma unroll
                for (int nd = 0; nd < 4; ++nd)
                    o_acc[nd] = __builtin_amdgcn_mfma_f32_16x16x32_bf16(
                        pa, vfrag(cur, nd * 16 + lr, ks * 4 + lg), o_acc[nd], 0, 0, 0);
            }
            __builtin_amdgcn_s_setprio(0);
            __syncthreads();   // all reads of cur done; next tile fully staged
        }

        // normalize + store to [b*T+t][h*64+d]
        const int b = bh >> 4, h = bh & 15;
        const float linv = 1.0f / l_s;
        #pragma unroll
        for (int r = 0; r < 4; ++r) {
            const float li = __shfl(linv, lg * 4 + r);
            const int q = q0 + qw + lg * 4 + r;
            #pragma unroll
            for (int nd = 0; nd < 4; ++nd) {
                const int d = nd * 16 + lr;
                Out[((size_t)(b * T_ + q)) * D_ + h * HD_ + d] = (bf16)(o_acc[nd][r] * li);
            }
        }
    }
}

// ---------------- launch ----------------
extern "C" void kernel_launch(void* const* d_in, const int* in_sizes, int n_in,
                              void* d_out, int out_size, void* d_ws, size_t ws_size,
                              hipStream_t stream) {
    const float* x  = (const float*)d_in[0];
    const float* Wq = (const float*)d_in[1];
    const float* bq = (const float*)d_in[2];
    const float* Wk = (const float*)d_in[3];
    const float* bk = (const float*)d_in[4];
    const float* Wv = (const float*)d_in[5];
    const float* bv = (const float*)d_in[6];
    const float* Wo = (const float*)d_in[7];
    const float* bo = (const float*)d_in[8];
    float* out = (float*)d_out;

    char* ws = (char*)d_ws;
    bf16* xb   = (bf16*)(ws);                         // 8 MB  [4096][1024]
    bf16* WqT  = (bf16*)(ws + ( 8u << 20));           // 2 MB  [1024][1024]
    bf16* WkT  = (bf16*)(ws + (10u << 20));
    bf16* WvT  = (bf16*)(ws + (12u << 20));
    bf16* WoT  = (bf16*)(ws + (14u << 20));
    bf16* Qb   = (bf16*)(ws + (16u << 20));           // 8 MB  [32][2048][64]
    bf16* Kb   = (bf16*)(ws + (24u << 20));
    bf16* Vtb  = (bf16*)(ws + (32u << 20));           // 8 MB  [32][64][2048]
    bf16* attn = (bf16*)(ws + (40u << 20));           // 8 MB  [4096][1024]

    prep_kernel<<<dim3(32, 32, 5), 256, 0, stream>>>(
        x, xb, Wq, WqT, Wk, WkT, Wv, WvT, Wo, WoT);

    qkv128_kernel<<<768, 256, 0, stream>>>(xb, WqT, bq, Qb, WkT, bk, Kb, WvT, bv, Vtb);

    attn_kernel<<<512, 256, 0, stream>>>(Qb, Kb, Vtb, attn);

    gemm_out_kernel<<<dim3(32, 8), 256, 0, stream>>>(attn, WoT, bo, out);
}